// Round 1
// baseline (537.941 us; speedup 1.0000x reference)
//
#include <hip/hip_runtime.h>
#include <hip/hip_bf16.h>

#define NT 3072
#define DIN_ 512
#define NH 16
#define DH 64
#define HDIM 1024

typedef unsigned short u16;
typedef short short8 __attribute__((ext_vector_type(8)));
typedef float f32x4 __attribute__((ext_vector_type(4)));
typedef __bf16 bf16x8 __attribute__((ext_vector_type(8)));

__device__ __forceinline__ u16 f2bf(float f){
  union { float f; unsigned u; } v; v.f = f;
  unsigned r = v.u + 0x7fffu + ((v.u >> 16) & 1u);
  return (u16)(r >> 16);
}
__device__ __forceinline__ float bf2f(u16 b){
  union { unsigned u; float f; } v; v.u = ((unsigned)b) << 16;
  return v.f;
}

// ---------------- prep: bm = mask ? bias : -1e30 (bf16); bias passthrough ----
__global__ __launch_bounds__(256) void prep_k(
    const float* __restrict__ bias, const int* __restrict__ mask,
    u16* __restrict__ bm, float* __restrict__ bias_out)
{
  int i = blockIdx.x * 256 + threadIdx.x;   // indexes groups of 4 elements
  f32x4 b = ((const f32x4*)bias)[i];
  int4 m = ((const int4*)mask)[i];
  ((f32x4*)bias_out)[i] = b;
  const int mm[4] = {m.x, m.y, m.z, m.w};
  union { u16 s[4]; unsigned long long ll; } pk;
  #pragma unroll
  for (int j = 0; j < 4; ++j)
    pk.s[j] = mm[j] ? f2bf(b[j]) : f2bf(-1e30f);
  ((unsigned long long*)bm)[i] = pk.ll;
}

// ---------------- generic 128x128 bf16-MFMA GEMM: C = A @ W^T + bvec --------
// A: [M,K] (fp32 or bf16), W: [Nc,K] fp32, C: [M,Nc]
// EPI 0: bf16 out, x = (acc+b)*scale     (projections; q uses scale=0.125)
// EPI 1: bf16 out, x = mish(acc+b)
// EPI 2: f32 out,  x = acc+b
template<int A_BF16, int EPI>
__global__ __launch_bounds__(256) void gemm_k(
    const void* __restrict__ Aptr, const float* __restrict__ W,
    const float* __restrict__ bvec, void* __restrict__ Cptr,
    int M, int Nc, int K, float scale)
{
  __shared__ __align__(16) u16 As[128*40];
  __shared__ __align__(16) u16 Bs[128*40];
  const int tid = threadIdx.x;
  const int lane = tid & 63;
  const int wid = tid >> 6;
  const int wr = wid >> 1, wc = wid & 1;
  const int g = lane >> 4, lr = lane & 15;
  const int bm0 = blockIdx.x * 128;
  const int bn0 = blockIdx.y * 128;

  f32x4 acc[4][4] = {};

  for (int k0 = 0; k0 < K; k0 += 32) {
    __syncthreads();
    if (A_BF16) {
      const u16* A = (const u16*)Aptr;
      #pragma unroll
      for (int it = 0; it < 2; ++it) {
        int e = it*2048 + tid*8;
        int r = e >> 5, kk = e & 31;
        *(short8*)&As[r*40 + kk] = *(const short8*)&A[(size_t)(bm0+r)*K + k0 + kk];
      }
    } else {
      const float* A = (const float*)Aptr;
      #pragma unroll
      for (int it = 0; it < 4; ++it) {
        int e = it*1024 + tid*4;
        int r = e >> 5, kk = e & 31;
        f32x4 v = *(const f32x4*)&A[(size_t)(bm0+r)*K + k0 + kk];
        union { u16 s[4]; unsigned long long ll; } pk;
        #pragma unroll
        for (int jj = 0; jj < 4; ++jj) pk.s[jj] = f2bf(v[jj]);
        *(unsigned long long*)&As[r*40 + kk] = pk.ll;
      }
    }
    {
      #pragma unroll
      for (int it = 0; it < 4; ++it) {
        int e = it*1024 + tid*4;
        int r = e >> 5, kk = e & 31;
        f32x4 v = *(const f32x4*)&W[(size_t)(bn0+r)*K + k0 + kk];
        union { u16 s[4]; unsigned long long ll; } pk;
        #pragma unroll
        for (int jj = 0; jj < 4; ++jj) pk.s[jj] = f2bf(v[jj]);
        *(unsigned long long*)&Bs[r*40 + kk] = pk.ll;
      }
    }
    __syncthreads();
    bf16x8 af[4], bfr[4];
    #pragma unroll
    for (int m = 0; m < 4; ++m)
      af[m] = *(const bf16x8*)&As[(wr*64 + m*16 + lr)*40 + g*8];
    #pragma unroll
    for (int n = 0; n < 4; ++n)
      bfr[n] = *(const bf16x8*)&Bs[(wc*64 + n*16 + lr)*40 + g*8];
    #pragma unroll
    for (int m = 0; m < 4; ++m)
      #pragma unroll
      for (int n = 0; n < 4; ++n)
        acc[m][n] = __builtin_amdgcn_mfma_f32_16x16x32_bf16(af[m], bfr[n], acc[m][n], 0, 0, 0);
  }

  #pragma unroll
  for (int m = 0; m < 4; ++m) {
    const int row0 = bm0 + wr*64 + m*16 + g*4;
    #pragma unroll
    for (int n = 0; n < 4; ++n) {
      const int col = bn0 + wc*64 + n*16 + lr;
      const float bb = bvec[col];
      #pragma unroll
      for (int j = 0; j < 4; ++j) {
        float x = acc[m][n][j] + bb;
        if (EPI == 0) x *= scale;
        if (EPI == 1) {
          float sp = (x > 15.f) ? x : log1pf(__expf(x));
          x = x * tanhf(sp);
        }
        if (EPI == 2)
          ((float*)Cptr)[(size_t)(row0+j)*Nc + col] = x;
        else
          ((u16*)Cptr)[(size_t)(row0+j)*Nc + col] = f2bf(x);
      }
    }
  }
}

// ---------------- flash attention: 64 q-rows x 1 head per block -------------
// qh pre-scaled by 1/sqrt(D). bm is bf16 masked bias.
__global__ __launch_bounds__(256) void attn_k(
    const u16* __restrict__ qh, const u16* __restrict__ kh,
    const u16* __restrict__ vh, const u16* __restrict__ bm,
    u16* __restrict__ vals)
{
  __shared__ __align__(128) u16 Qs[64*72];
  __shared__ __align__(128) u16 Ks[64*72];
  __shared__ __align__(128) u16 Vts[64*72];   // transposed [d][c], XOR-swizzled
  __shared__ __align__(128) u16 Bms[64*72];
  __shared__ __align__(128) u16 Ps[4][16*72]; // per-wave P tile

  const int tid = threadIdx.x;
  const int lane = tid & 63;
  const int w = tid >> 6;
  const int g = lane >> 4, lr = lane & 15;
  const int i0 = blockIdx.x * 64;
  const int h = blockIdx.y;
  const int hoff = h * DH;

  // stage Q tile [64][64]
  #pragma unroll
  for (int it = 0; it < 2; ++it) {
    int c = it*256 + tid;
    int r = c >> 3, co = (c & 7) * 8;
    *(short8*)&Qs[r*72 + co] = *(const short8*)&qh[(size_t)(i0 + r)*HDIM + hoff + co];
  }
  __syncthreads();
  bf16x8 qf[2];
  #pragma unroll
  for (int kc = 0; kc < 2; ++kc)
    qf[kc] = *(const bf16x8*)&Qs[(w*16 + lr)*72 + kc*32 + g*8];

  f32x4 Oa[4] = {};
  float mrow[4], lsum[4];
  #pragma unroll
  for (int r = 0; r < 4; ++r) { mrow[r] = -1e30f; lsum[r] = 0.f; }

  for (int j = 0; j < NT/64; ++j) {
    __syncthreads();
    const int c0 = j * 64;
    // stage K [64][64]
    #pragma unroll
    for (int it = 0; it < 2; ++it) {
      int c = it*256 + tid;
      int r = c >> 3, co = (c & 7) * 8;
      *(short8*)&Ks[r*72 + co] = *(const short8*)&kh[(size_t)(c0 + r)*HDIM + hoff + co];
    }
    // stage masked-bias tile [64][64]
    #pragma unroll
    for (int it = 0; it < 2; ++it) {
      int c = it*256 + tid;
      int r = c >> 3, co = (c & 7) * 8;
      *(short8*)&Bms[r*72 + co] = *(const short8*)&bm[(size_t)(i0 + r)*NT + c0 + co];
    }
    // stage V transposed: Vts[d][c], swizzled
    #pragma unroll
    for (int it = 0; it < 2; ++it) {
      int c = it*256 + tid;
      int vr = c >> 3, dco = (c & 7) * 8;
      short8 v = *(const short8*)&vh[(size_t)(c0 + vr)*HDIM + hoff + dco];
      #pragma unroll
      for (int jj = 0; jj < 8; ++jj) {
        int d = dco + jj;
        int byte = d*144 + vr*2;
        byte ^= ((d >> 3) & 7) << 4;
        *(u16*)((char*)Vts + byte) = (u16)v[jj];
      }
    }
    __syncthreads();

    // S = Q K^T  (16 rows x 64 cols per wave)
    f32x4 Sa[4] = {};
    #pragma unroll
    for (int kc = 0; kc < 2; ++kc) {
      #pragma unroll
      for (int n = 0; n < 4; ++n) {
        bf16x8 kb = *(const bf16x8*)&Ks[(n*16 + lr)*72 + kc*32 + g*8];
        Sa[n] = __builtin_amdgcn_mfma_f32_16x16x32_bf16(qf[kc], kb, Sa[n], 0, 0, 0);
      }
    }
    // bias add + online softmax
    float P[4][4];
    float alpha[4];
    #pragma unroll
    for (int jr = 0; jr < 4; ++jr) {
      const int r = g*4 + jr;
      float s0[4];
      float tmax = -1e30f;
      #pragma unroll
      for (int n = 0; n < 4; ++n) {
        float bb = bf2f(Bms[(w*16 + r)*72 + n*16 + lr]);
        float s = Sa[n][jr] + bb;
        s0[n] = s;
        tmax = fmaxf(tmax, s);
      }
      #pragma unroll
      for (int msk = 1; msk < 16; msk <<= 1)
        tmax = fmaxf(tmax, __shfl_xor(tmax, msk, 64));
      float mnew = fmaxf(mrow[jr], tmax);
      alpha[jr] = __expf(mrow[jr] - mnew);
      float psum = 0.f;
      #pragma unroll
      for (int n = 0; n < 4; ++n) {
        float p = __expf(s0[n] - mnew);
        P[n][jr] = p;
        psum += p;
      }
      #pragma unroll
      for (int msk = 1; msk < 16; msk <<= 1)
        psum += __shfl_xor(psum, msk, 64);
      lsum[jr] = lsum[jr]*alpha[jr] + psum;
      mrow[jr] = mnew;
    }
    #pragma unroll
    for (int n = 0; n < 4; ++n)
      #pragma unroll
      for (int jr = 0; jr < 4; ++jr)
        Oa[n][jr] *= alpha[jr];
    // write P (bf16) to per-wave LDS, C-layout -> A-layout round trip
    #pragma unroll
    for (int n = 0; n < 4; ++n)
      #pragma unroll
      for (int jr = 0; jr < 4; ++jr)
        Ps[w][(g*4 + jr)*72 + n*16 + lr] = f2bf(P[n][jr]);
    // O += P @ V
    #pragma unroll
    for (int kc = 0; kc < 2; ++kc) {
      bf16x8 pa = *(const bf16x8*)&Ps[w][lr*72 + kc*32 + g*8];
      #pragma unroll
      for (int n = 0; n < 4; ++n) {
        int d = n*16 + lr;
        int byte = d*144 + (kc*32 + g*8)*2;
        byte ^= ((d >> 3) & 7) << 4;
        bf16x8 vb = *(const bf16x8*)((const char*)Vts + byte);
        Oa[n] = __builtin_amdgcn_mfma_f32_16x16x32_bf16(pa, vb, Oa[n], 0, 0, 0);
      }
    }
  }

  // normalize + store
  #pragma unroll
  for (int n = 0; n < 4; ++n) {
    #pragma unroll
    for (int jr = 0; jr < 4; ++jr) {
      float o = Oa[n][jr] / lsum[jr];
      int row = i0 + w*16 + g*4 + jr;
      vals[(size_t)row*HDIM + hoff + n*16 + lr] = f2bf(o);
    }
  }
}

extern "C" void kernel_launch(void* const* d_in, const int* in_sizes, int n_in,
                              void* d_out, int out_size, void* d_ws, size_t ws_size,
                              hipStream_t stream) {
  const float* q    = (const float*)d_in[0];
  const float* k    = (const float*)d_in[1];
  const float* v    = (const float*)d_in[2];
  const float* bias = (const float*)d_in[3];
  const int*   mask = (const int*)d_in[4];
  const float* Wq   = (const float*)d_in[5];
  const float* bq   = (const float*)d_in[6];
  const float* Wk   = (const float*)d_in[7];
  const float* bk   = (const float*)d_in[8];
  const float* Wv   = (const float*)d_in[9];
  const float* bv   = (const float*)d_in[10];
  const float* Wo1  = (const float*)d_in[11];
  const float* bo1  = (const float*)d_in[12];
  const float* Wo2  = (const float*)d_in[13];
  const float* bo2  = (const float*)d_in[14];

  float* out = (float*)d_out;
  float* bias_out = out + (size_t)NT * DIN_;

  char* ws = (char*)d_ws;
  u16* bm   = (u16*)ws; ws += (size_t)NT*NT*2;
  u16* qh   = (u16*)ws; ws += (size_t)NT*HDIM*2;
  u16* kh   = (u16*)ws; ws += (size_t)NT*HDIM*2;
  u16* vh   = (u16*)ws; ws += (size_t)NT*HDIM*2;
  u16* vals = (u16*)ws; ws += (size_t)NT*HDIM*2;
  u16* t1   = qh;  // reuse: qh dead after attention

  // prep: masked bias + bias passthrough output
  prep_k<<<dim3(NT*NT/4/256), 256, 0, stream>>>(bias, mask, bm, bias_out);

  // projections (q scaled by 1/sqrt(D))
  dim3 gp(NT/128, HDIM/128);
  gemm_k<0,0><<<gp, 256, 0, stream>>>(q, Wq, bq, qh, NT, HDIM, DIN_, 0.125f);
  gemm_k<0,0><<<gp, 256, 0, stream>>>(k, Wk, bk, kh, NT, HDIM, DIN_, 1.0f);
  gemm_k<0,0><<<gp, 256, 0, stream>>>(v, Wv, bv, vh, NT, HDIM, DIN_, 1.0f);

  // attention
  attn_k<<<dim3(NT/64, NH), 256, 0, stream>>>(qh, kh, vh, bm, vals);

  // o_proj: mish(vals @ Wo1^T) @ Wo2^T
  gemm_k<1,1><<<dim3(NT/128, HDIM/128), 256, 0, stream>>>(vals, Wo1, bo1, t1, NT, HDIM, HDIM, 1.0f);
  gemm_k<1,2><<<dim3(NT/128, DIN_/128), 256, 0, stream>>>(t1, Wo2, bo2, out, NT, DIN_, HDIM, 1.0f);
}

// Round 5
// 486.112 us; speedup vs baseline: 1.1066x; 1.1066x over previous
//
#include <hip/hip_runtime.h>
#include <hip/hip_bf16.h>

#define NT 3072
#define DIN_ 512
#define NH 16
#define DH 64
#define HDIM 1024

typedef unsigned short u16;
typedef unsigned int u32;
typedef short short8 __attribute__((ext_vector_type(8)));
typedef float f32x4 __attribute__((ext_vector_type(4)));
typedef __bf16 bf16x8 __attribute__((ext_vector_type(8)));

__device__ __forceinline__ u16 f2bf(float f){
  union { float f; unsigned u; } v; v.f = f;
  unsigned r = v.u + 0x7fffu + ((v.u >> 16) & 1u);
  return (u16)(r >> 16);
}
__device__ __forceinline__ float bf2f(u16 b){
  union { unsigned u; float f; } v; v.u = ((unsigned)b) << 16;
  return v.f;
}

// ---------------- prep: bm = mask ? bias : -1e30 (bf16); bias passthrough ----
__global__ __launch_bounds__(256) void prep_k(
    const float* __restrict__ bias, const int* __restrict__ mask,
    u16* __restrict__ bm, float* __restrict__ bias_out)
{
  int i = blockIdx.x * 256 + threadIdx.x;   // groups of 4 elements
  f32x4 b = ((const f32x4*)bias)[i];
  int4 m = ((const int4*)mask)[i];
  ((f32x4*)bias_out)[i] = b;
  const int mm[4] = {m.x, m.y, m.z, m.w};
  union { u16 s[4]; unsigned long long ll; } pk;
  #pragma unroll
  for (int j = 0; j < 4; ++j)
    pk.s[j] = mm[j] ? f2bf(b[j]) : f2bf(-1e30f);
  ((unsigned long long*)bm)[i] = pk.ll;
}

// ---------------- shared 128x128 bf16-MFMA GEMM body: C = A @ W^T + bvec ----
// EPI 0: bf16 out, x = (acc+b)*scale ; EPI 1: bf16 out, mish ; EPI 2: f32 out
template<int A_BF16, int EPI>
__device__ __forceinline__ void gemm_body(
    const void* __restrict__ Aptr, const float* __restrict__ W,
    const float* __restrict__ bvec, void* __restrict__ Cptr,
    int Nc, int K, float scale, int bm0, int bn0,
    u16* As, u16* Bs)
{
  const int tid = threadIdx.x;
  const int lane = tid & 63;
  const int wid = tid >> 6;
  const int wr = wid >> 1, wc = wid & 1;
  const int g = lane >> 4, lr = lane & 15;

  f32x4 acc[4][4] = {};

  for (int k0 = 0; k0 < K; k0 += 32) {
    __syncthreads();
    if (A_BF16) {
      const u16* A = (const u16*)Aptr;
      #pragma unroll
      for (int it = 0; it < 2; ++it) {
        int e = it*2048 + tid*8;
        int r = e >> 5, kk = e & 31;
        *(short8*)&As[r*40 + kk] = *(const short8*)&A[(size_t)(bm0+r)*K + k0 + kk];
      }
    } else {
      const float* A = (const float*)Aptr;
      #pragma unroll
      for (int it = 0; it < 4; ++it) {
        int e = it*1024 + tid*4;
        int r = e >> 5, kk = e & 31;
        f32x4 v = *(const f32x4*)&A[(size_t)(bm0+r)*K + k0 + kk];
        union { u16 s[4]; unsigned long long ll; } pk;
        #pragma unroll
        for (int jj = 0; jj < 4; ++jj) pk.s[jj] = f2bf(v[jj]);
        *(unsigned long long*)&As[r*40 + kk] = pk.ll;
      }
    }
    {
      #pragma unroll
      for (int it = 0; it < 4; ++it) {
        int e = it*1024 + tid*4;
        int r = e >> 5, kk = e & 31;
        f32x4 v = *(const f32x4*)&W[(size_t)(bn0+r)*K + k0 + kk];
        union { u16 s[4]; unsigned long long ll; } pk;
        #pragma unroll
        for (int jj = 0; jj < 4; ++jj) pk.s[jj] = f2bf(v[jj]);
        *(unsigned long long*)&Bs[r*40 + kk] = pk.ll;
      }
    }
    __syncthreads();
    bf16x8 af[4], bfr[4];
    #pragma unroll
    for (int m = 0; m < 4; ++m)
      af[m] = *(const bf16x8*)&As[(wr*64 + m*16 + lr)*40 + g*8];
    #pragma unroll
    for (int n = 0; n < 4; ++n)
      bfr[n] = *(const bf16x8*)&Bs[(wc*64 + n*16 + lr)*40 + g*8];
    #pragma unroll
    for (int m = 0; m < 4; ++m)
      #pragma unroll
      for (int n = 0; n < 4; ++n)
        acc[m][n] = __builtin_amdgcn_mfma_f32_16x16x32_bf16(af[m], bfr[n], acc[m][n], 0, 0, 0);
  }

  #pragma unroll
  for (int m = 0; m < 4; ++m) {
    const int row0 = bm0 + wr*64 + m*16 + g*4;
    #pragma unroll
    for (int n = 0; n < 4; ++n) {
      const int col = bn0 + wc*64 + n*16 + lr;
      const float bb = bvec[col];
      #pragma unroll
      for (int j = 0; j < 4; ++j) {
        float x = acc[m][n][j] + bb;
        if (EPI == 0) x *= scale;
        if (EPI == 1) {
          float sp = (x > 15.f) ? x : log1pf(__expf(x));
          x = x * tanhf(sp);
        }
        if (EPI == 2)
          ((float*)Cptr)[(size_t)(row0+j)*Nc + col] = x;
        else
          ((u16*)Cptr)[(size_t)(row0+j)*Nc + col] = f2bf(x);
      }
    }
  }
}

template<int A_BF16, int EPI>
__global__ __launch_bounds__(256) void gemm_k(
    const void* __restrict__ Aptr, const float* __restrict__ W,
    const float* __restrict__ bvec, void* __restrict__ Cptr,
    int Nc, int K, float scale)
{
  __shared__ __align__(16) u16 As[128*40];
  __shared__ __align__(16) u16 Bs[128*40];
  gemm_body<A_BF16, EPI>(Aptr, W, bvec, Cptr, Nc, K, scale,
                         blockIdx.x*128, blockIdx.y*128, As, Bs);
}

// fused q/k/v projections: blockIdx.y selects source (grid 24 x 24)
__global__ __launch_bounds__(256) void qkv_k(
    const float* __restrict__ q, const float* __restrict__ k,
    const float* __restrict__ v,
    const float* __restrict__ Wq, const float* __restrict__ bq,
    const float* __restrict__ Wk, const float* __restrict__ bk,
    const float* __restrict__ Wv, const float* __restrict__ bv,
    u16* __restrict__ qh, u16* __restrict__ kh, u16* __restrict__ vh)
{
  __shared__ __align__(16) u16 As[128*40];
  __shared__ __align__(16) u16 Bs[128*40];
  const int sel = blockIdx.y >> 3;
  const float* A    = sel == 0 ? q  : (sel == 1 ? k  : v);
  const float* W    = sel == 0 ? Wq : (sel == 1 ? Wk : Wv);
  const float* bvec = sel == 0 ? bq : (sel == 1 ? bk : bv);
  u16* C            = sel == 0 ? qh : (sel == 1 ? kh : vh);
  const float scale = sel == 0 ? 0.125f : 1.0f;
  gemm_body<0, 0>(A, W, bvec, C, HDIM, DIN_, scale,
                  blockIdx.x*128, (blockIdx.y & 7)*128, As, Bs);
}

// ---------------- flash attention: 64 q-rows x 1 head per block -------------
// ROUND-1 VERBATIM structure (known-good) + rule-18 hardening at the P
// LDS round-trip. qh pre-scaled by 1/sqrt(D). bm is bf16 masked bias.
__global__ __launch_bounds__(256) void attn_k(
    const u16* __restrict__ qh, const u16* __restrict__ kh,
    const u16* __restrict__ vh, const u16* __restrict__ bm,
    u16* __restrict__ vals)
{
  __shared__ __align__(16) u16 Qs[64*72];
  __shared__ __align__(16) u16 Ks[64*72];
  __shared__ __align__(16) u16 Vts[64*72];   // transposed [d][c], XOR-swizzled
  __shared__ __align__(16) u16 Bms[64*72];
  __shared__ __align__(16) u16 Ps[4][16*72]; // per-wave P tile

  const int tid = threadIdx.x;
  const int lane = tid & 63;
  const int w = tid >> 6;
  const int g = lane >> 4, lr = lane & 15;
  const int i0 = blockIdx.x * 64;
  const int hoff = blockIdx.y * DH;

  // stage Q tile [64][64]
  #pragma unroll
  for (int it = 0; it < 2; ++it) {
    int c = it*256 + tid;
    int r = c >> 3, co = (c & 7) * 8;
    *(short8*)&Qs[r*72 + co] = *(const short8*)&qh[(size_t)(i0 + r)*HDIM + hoff + co];
  }
  __syncthreads();
  bf16x8 qf[2];
  #pragma unroll
  for (int kc = 0; kc < 2; ++kc)
    qf[kc] = *(const bf16x8*)&Qs[(w*16 + lr)*72 + kc*32 + g*8];

  f32x4 Oa[4] = {};
  float mrow[4], lsum[4];
  #pragma unroll
  for (int r = 0; r < 4; ++r) { mrow[r] = -1e30f; lsum[r] = 0.f; }

  for (int j = 0; j < NT/64; ++j) {
    __syncthreads();
    const int c0 = j * 64;
    // stage K [64][64]
    #pragma unroll
    for (int it = 0; it < 2; ++it) {
      int c = it*256 + tid;
      int r = c >> 3, co = (c & 7) * 8;
      *(short8*)&Ks[r*72 + co] = *(const short8*)&kh[(size_t)(c0 + r)*HDIM + hoff + co];
    }
    // stage masked-bias tile [64][64]
    #pragma unroll
    for (int it = 0; it < 2; ++it) {
      int c = it*256 + tid;
      int r = c >> 3, co = (c & 7) * 8;
      *(short8*)&Bms[r*72 + co] = *(const short8*)&bm[(size_t)(i0 + r)*NT + c0 + co];
    }
    // stage V transposed: Vts[d][c], swizzled
    #pragma unroll
    for (int it = 0; it < 2; ++it) {
      int c = it*256 + tid;
      int vr = c >> 3, dco = (c & 7) * 8;
      short8 v = *(const short8*)&vh[(size_t)(c0 + vr)*HDIM + hoff + dco];
      #pragma unroll
      for (int jj = 0; jj < 8; ++jj) {
        int d = dco + jj;
        int byte = d*144 + vr*2;
        byte ^= ((d >> 3) & 7) << 4;
        *(u16*)((char*)Vts + byte) = (u16)v[jj];
      }
    }
    __syncthreads();

    // S = Q K^T  (16 rows x 64 cols per wave)
    f32x4 Sa[4] = {};
    #pragma unroll
    for (int kc = 0; kc < 2; ++kc) {
      #pragma unroll
      for (int n = 0; n < 4; ++n) {
        bf16x8 kb = *(const bf16x8*)&Ks[(n*16 + lr)*72 + kc*32 + g*8];
        Sa[n] = __builtin_amdgcn_mfma_f32_16x16x32_bf16(qf[kc], kb, Sa[n], 0, 0, 0);
      }
    }
    // bias add + online softmax
    float P[4][4];
    float alpha[4];
    #pragma unroll
    for (int jr = 0; jr < 4; ++jr) {
      const int r = g*4 + jr;
      float s0[4];
      float tmax = -1e30f;
      #pragma unroll
      for (int n = 0; n < 4; ++n) {
        float bb = bf2f(Bms[(w*16 + r)*72 + n*16 + lr]);
        float s = Sa[n][jr] + bb;
        s0[n] = s;
        tmax = fmaxf(tmax, s);
      }
      #pragma unroll
      for (int msk = 1; msk < 16; msk <<= 1)
        tmax = fmaxf(tmax, __shfl_xor(tmax, msk, 64));
      float mnew = fmaxf(mrow[jr], tmax);
      alpha[jr] = __expf(mrow[jr] - mnew);
      float psum = 0.f;
      #pragma unroll
      for (int n = 0; n < 4; ++n) {
        float p = __expf(s0[n] - mnew);
        P[n][jr] = p;
        psum += p;
      }
      #pragma unroll
      for (int msk = 1; msk < 16; msk <<= 1)
        psum += __shfl_xor(psum, msk, 64);
      lsum[jr] = lsum[jr]*alpha[jr] + psum;
      mrow[jr] = mnew;
    }
    #pragma unroll
    for (int n = 0; n < 4; ++n)
      #pragma unroll
      for (int jr = 0; jr < 4; ++jr)
        Oa[n][jr] *= alpha[jr];
    // write P (bf16) to per-wave LDS, C-layout -> A-layout round trip
    #pragma unroll
    for (int n = 0; n < 4; ++n)
      #pragma unroll
      for (int jr = 0; jr < 4; ++jr)
        Ps[w][(g*4 + jr)*72 + n*16 + lr] = f2bf(P[n][jr]);
    // rule-18 hardening: all P ds_writes retire before any P ds_read; the
    // sched_barrier pins register-only MFMA from hoisting past the waitcnt
    __asm__ volatile("s_waitcnt lgkmcnt(0)" ::: "memory");
    __builtin_amdgcn_sched_barrier(0);
    // O += P @ V
    #pragma unroll
    for (int kc = 0; kc < 2; ++kc) {
      bf16x8 pa = *(const bf16x8*)&Ps[w][lr*72 + kc*32 + g*8];
      #pragma unroll
      for (int n = 0; n < 4; ++n) {
        int d = n*16 + lr;
        int byte = d*144 + (kc*32 + g*8)*2;
        byte ^= ((d >> 3) & 7) << 4;
        bf16x8 vb = *(const bf16x8*)((const char*)Vts + byte);
        Oa[n] = __builtin_amdgcn_mfma_f32_16x16x32_bf16(pa, vb, Oa[n], 0, 0, 0);
      }
    }
  }

  // normalize + store
  #pragma unroll
  for (int n = 0; n < 4; ++n) {
    #pragma unroll
    for (int jr = 0; jr < 4; ++jr) {
      float o = Oa[n][jr] / lsum[jr];
      int row = i0 + w*16 + g*4 + jr;
      vals[(size_t)row*HDIM + hoff + n*16 + lr] = f2bf(o);
    }
  }
}

extern "C" void kernel_launch(void* const* d_in, const int* in_sizes, int n_in,
                              void* d_out, int out_size, void* d_ws, size_t ws_size,
                              hipStream_t stream) {
  const float* q    = (const float*)d_in[0];
  const float* k    = (const float*)d_in[1];
  const float* v    = (const float*)d_in[2];
  const float* bias = (const float*)d_in[3];
  const int*   mask = (const int*)d_in[4];
  const float* Wq   = (const float*)d_in[5];
  const float* bq   = (const float*)d_in[6];
  const float* Wk   = (const float*)d_in[7];
  const float* bk   = (const float*)d_in[8];
  const float* Wv   = (const float*)d_in[9];
  const float* bv   = (const float*)d_in[10];
  const float* Wo1  = (const float*)d_in[11];
  const float* bo1  = (const float*)d_in[12];
  const float* Wo2  = (const float*)d_in[13];
  const float* bo2  = (const float*)d_in[14];

  float* out = (float*)d_out;
  float* bias_out = out + (size_t)NT * DIN_;

  char* ws = (char*)d_ws;
  u16* bm   = (u16*)ws; ws += (size_t)NT*NT*2;
  u16* qh   = (u16*)ws; ws += (size_t)NT*HDIM*2;
  u16* kh   = (u16*)ws; ws += (size_t)NT*HDIM*2;
  u16* vh   = (u16*)ws; ws += (size_t)NT*HDIM*2;
  u16* vals = (u16*)ws; ws += (size_t)NT*HDIM*2;
  u16* t1   = qh;  // reuse: qh dead after attention

  prep_k<<<dim3(NT*NT/4/256), 256, 0, stream>>>(bias, mask, bm, bias_out);

  // fused projections (q scaled by 1/sqrt(D))
  qkv_k<<<dim3(NT/128, 24), 256, 0, stream>>>(q, k, v, Wq, bq, Wk, bk, Wv, bv,
                                              qh, kh, vh);

  attn_k<<<dim3(NT/64, NH), 256, 0, stream>>>(qh, kh, vh, bm, vals);

  gemm_k<1,1><<<dim3(NT/128, HDIM/128), 256, 0, stream>>>(vals, Wo1, bo1, t1, HDIM, HDIM, 1.0f);
  gemm_k<1,2><<<dim3(NT/128, DIN_/128), 256, 0, stream>>>(t1, Wo2, bo2, out, DIN_, HDIM, 1.0f);
}

// Round 7
// 418.103 us; speedup vs baseline: 1.2866x; 1.1627x over previous
//
#include <hip/hip_runtime.h>
#include <hip/hip_bf16.h>

#define NT 3072
#define DIN_ 512
#define NH 16
#define DH 64
#define HDIM 1024

typedef unsigned short u16;
typedef unsigned int u32;
typedef short short8 __attribute__((ext_vector_type(8)));
typedef float f32x4 __attribute__((ext_vector_type(4)));
typedef __bf16 bf16x8 __attribute__((ext_vector_type(8)));

__device__ __forceinline__ u16 f2bf(float f){
  union { float f; unsigned u; } v; v.f = f;
  unsigned r = v.u + 0x7fffu + ((v.u >> 16) & 1u);
  return (u16)(r >> 16);
}
__device__ __forceinline__ float bf2f(u16 b){
  union { unsigned u; float f; } v; v.u = ((unsigned)b) << 16;
  return v.f;
}

// ---------------- prep: bm = mask ? bias : -1e30 (bf16); bias passthrough ----
__global__ __launch_bounds__(256) void prep_k(
    const float* __restrict__ bias, const int* __restrict__ mask,
    u16* __restrict__ bm, float* __restrict__ bias_out)
{
  int i = blockIdx.x * 256 + threadIdx.x;   // groups of 4 elements
  f32x4 b = ((const f32x4*)bias)[i];
  int4 m = ((const int4*)mask)[i];
  ((f32x4*)bias_out)[i] = b;
  const int mm[4] = {m.x, m.y, m.z, m.w};
  union { u16 s[4]; unsigned long long ll; } pk;
  #pragma unroll
  for (int j = 0; j < 4; ++j)
    pk.s[j] = mm[j] ? f2bf(b[j]) : f2bf(-1e30f);
  ((unsigned long long*)bm)[i] = pk.ll;
}

// ---------------- convert the 5 weight matrices to bf16 (once) --------------
__global__ __launch_bounds__(256) void cvtw_k(
    const float* __restrict__ Wq, const float* __restrict__ Wk,
    const float* __restrict__ Wv, const float* __restrict__ Wo1,
    const float* __restrict__ Wo2,
    u16* __restrict__ wqb, u16* __restrict__ wkb, u16* __restrict__ wvb,
    u16* __restrict__ wo1b, u16* __restrict__ wo2b)
{
  const float* src; u16* dst; int n4;
  switch (blockIdx.y) {
    case 0: src = Wq;  dst = wqb;  n4 = HDIM*DIN_/4; break;
    case 1: src = Wk;  dst = wkb;  n4 = HDIM*DIN_/4; break;
    case 2: src = Wv;  dst = wvb;  n4 = HDIM*DIN_/4; break;
    case 3: src = Wo1; dst = wo1b; n4 = HDIM*HDIM/4; break;
    default: src = Wo2; dst = wo2b; n4 = DIN_*HDIM/4; break;
  }
  int i = blockIdx.x * 256 + threadIdx.x;
  if (i >= n4) return;
  f32x4 v = ((const f32x4*)src)[i];
  ushort4 o;
  o.x = f2bf(v[0]); o.y = f2bf(v[1]); o.z = f2bf(v[2]); o.w = f2bf(v[3]);
  ((ushort4*)dst)[i] = o;
}

// ---------------- shared 128x128 bf16-MFMA GEMM body: C = A @ W^T + bvec ----
// W pre-converted bf16. A fp32 (A_BF16=0) or bf16 (A_BF16=1).
// EPI 0: bf16 out, x = (acc+b)*scale ; EPI 1: bf16 out, mish ; EPI 2: f32 out
template<int A_BF16, int EPI>
__device__ __forceinline__ void gemm_body(
    const void* __restrict__ Aptr, const u16* __restrict__ W,
    const float* __restrict__ bvec, void* __restrict__ Cptr,
    int Nc, int K, float scale, int bm0, int bn0,
    u16* As, u16* Bs)
{
  const int tid = threadIdx.x;
  const int lane = tid & 63;
  const int wid = tid >> 6;
  const int wr = wid >> 1, wc = wid & 1;
  const int g = lane >> 4, lr = lane & 15;

  f32x4 acc[4][4] = {};

  for (int k0 = 0; k0 < K; k0 += 32) {
    __syncthreads();
    if (A_BF16) {
      const u16* A = (const u16*)Aptr;
      #pragma unroll
      for (int it = 0; it < 2; ++it) {
        int e = it*2048 + tid*8;
        int r = e >> 5, kk = e & 31;
        *(short8*)&As[r*40 + kk] = *(const short8*)&A[(size_t)(bm0+r)*K + k0 + kk];
      }
    } else {
      const float* A = (const float*)Aptr;
      #pragma unroll
      for (int it = 0; it < 4; ++it) {
        int e = it*1024 + tid*4;
        int r = e >> 5, kk = e & 31;
        f32x4 v = *(const f32x4*)&A[(size_t)(bm0+r)*K + k0 + kk];
        union { u16 s[4]; unsigned long long ll; } pk;
        #pragma unroll
        for (int jj = 0; jj < 4; ++jj) pk.s[jj] = f2bf(v[jj]);
        *(unsigned long long*)&As[r*40 + kk] = pk.ll;
      }
    }
    {
      #pragma unroll
      for (int it = 0; it < 2; ++it) {
        int e = it*2048 + tid*8;
        int r = e >> 5, kk = e & 31;
        *(short8*)&Bs[r*40 + kk] = *(const short8*)&W[(size_t)(bn0+r)*K + k0 + kk];
      }
    }
    __syncthreads();
    bf16x8 af[4], bfr[4];
    #pragma unroll
    for (int m = 0; m < 4; ++m)
      af[m] = *(const bf16x8*)&As[(wr*64 + m*16 + lr)*40 + g*8];
    #pragma unroll
    for (int n = 0; n < 4; ++n)
      bfr[n] = *(const bf16x8*)&Bs[(wc*64 + n*16 + lr)*40 + g*8];
    #pragma unroll
    for (int m = 0; m < 4; ++m)
      #pragma unroll
      for (int n = 0; n < 4; ++n)
        acc[m][n] = __builtin_amdgcn_mfma_f32_16x16x32_bf16(af[m], bfr[n], acc[m][n], 0, 0, 0);
  }

  #pragma unroll
  for (int m = 0; m < 4; ++m) {
    const int row0 = bm0 + wr*64 + m*16 + g*4;
    #pragma unroll
    for (int n = 0; n < 4; ++n) {
      const int col = bn0 + wc*64 + n*16 + lr;
      const float bb = bvec[col];
      #pragma unroll
      for (int j = 0; j < 4; ++j) {
        float x = acc[m][n][j] + bb;
        if (EPI == 0) x *= scale;
        if (EPI == 1) {
          float sp = (x > 15.f) ? x : log1pf(__expf(x));
          x = x * tanhf(sp);
        }
        if (EPI == 2)
          ((float*)Cptr)[(size_t)(row0+j)*Nc + col] = x;
        else
          ((u16*)Cptr)[(size_t)(row0+j)*Nc + col] = f2bf(x);
      }
    }
  }
}

template<int A_BF16, int EPI>
__global__ __launch_bounds__(256) void gemm_k(
    const void* __restrict__ Aptr, const u16* __restrict__ W,
    const float* __restrict__ bvec, void* __restrict__ Cptr,
    int Nc, int K, float scale)
{
  __shared__ __align__(16) u16 As[128*40];
  __shared__ __align__(16) u16 Bs[128*40];
  gemm_body<A_BF16, EPI>(Aptr, W, bvec, Cptr, Nc, K, scale,
                         blockIdx.x*128, blockIdx.y*128, As, Bs);
}

// fused q/k/v projections: blockIdx.y selects source (grid 24 x 24)
__global__ __launch_bounds__(256) void qkv_k(
    const float* __restrict__ q, const float* __restrict__ k,
    const float* __restrict__ v,
    const u16* __restrict__ wqb, const float* __restrict__ bq,
    const u16* __restrict__ wkb, const float* __restrict__ bk,
    const u16* __restrict__ wvb, const float* __restrict__ bv,
    u16* __restrict__ qh, u16* __restrict__ kh, u16* __restrict__ vh)
{
  __shared__ __align__(16) u16 As[128*40];
  __shared__ __align__(16) u16 Bs[128*40];
  const int sel = blockIdx.y >> 3;
  const float* A    = sel == 0 ? q   : (sel == 1 ? k   : v);
  const u16* W      = sel == 0 ? wqb : (sel == 1 ? wkb : wvb);
  const float* bvec = sel == 0 ? bq  : (sel == 1 ? bk  : bv);
  u16* C            = sel == 0 ? qh  : (sel == 1 ? kh  : vh);
  const float scale = sel == 0 ? 0.125f : 1.0f;
  gemm_body<0, 0>(A, W, bvec, C, HDIM, DIN_, scale,
                  blockIdx.x*128, (blockIdx.y & 7)*128, As, Bs);
}

// ---------------- flash attention: 64 q-rows x 1 head per block -------------
// BISECT HALF-STEP: swapped-QK softmax (S^T = mfma(K,Q), bias preloaded in
// accumulator, per-lane in-register softmax, 2 reduce shuffles) feeding the
// ROUND-1-VERBATIM PV + output store via the round-1 P LDS layout.
__global__ __launch_bounds__(256) void attn_k(
    const u16* __restrict__ qh, const u16* __restrict__ kh,
    const u16* __restrict__ vh, const u16* __restrict__ bm,
    u16* __restrict__ vals)
{
  __shared__ __align__(16) u16 Qs[64*72];
  __shared__ __align__(16) u16 Ks[64*72];
  __shared__ __align__(16) u16 Vts[64*72];   // transposed [d][c], XOR-swizzled
  __shared__ __align__(16) u16 Ps[4][16*72]; // per-wave P tile [q][key]

  const int tid = threadIdx.x;
  const int lane = tid & 63;
  const int w = tid >> 6;
  const int g = lane >> 4, lr = lane & 15;
  const int i0 = blockIdx.x * 64;
  const int hoff = blockIdx.y * DH;

  // stage Q tile [64][64]
  #pragma unroll
  for (int it = 0; it < 2; ++it) {
    int c = it*256 + tid;
    int r = c >> 3, co = (c & 7) * 8;
    *(short8*)&Qs[r*72 + co] = *(const short8*)&qh[(size_t)(i0 + r)*HDIM + hoff + co];
  }
  __syncthreads();
  // same bytes as round-1 (A-frag row=lr == B-frag col=lr)
  bf16x8 qf[2];
  #pragma unroll
  for (int kc = 0; kc < 2; ++kc)
    qf[kc] = *(const bf16x8*)&Qs[(w*16 + lr)*72 + kc*32 + g*8];

  f32x4 Oa[4] = {};
  float mr = -1e30f, ls = 0.f;                 // state for query row lr
  const size_t bmrow = (size_t)(i0 + w*16 + lr) * NT;

  for (int j = 0; j < NT/64; ++j) {
    const int c0 = j * 64;
    __syncthreads();
    // stage K [64][64]  (round-1 verbatim)
    #pragma unroll
    for (int it = 0; it < 2; ++it) {
      int c = it*256 + tid;
      int r = c >> 3, co = (c & 7) * 8;
      *(short8*)&Ks[r*72 + co] = *(const short8*)&kh[(size_t)(c0 + r)*HDIM + hoff + co];
    }
    // stage V transposed: Vts[d][c], swizzled  (round-1 verbatim)
    #pragma unroll
    for (int it = 0; it < 2; ++it) {
      int c = it*256 + tid;
      int vr = c >> 3, dco = (c & 7) * 8;
      short8 vv = *(const short8*)&vh[(size_t)(c0 + vr)*HDIM + hoff + dco];
      #pragma unroll
      for (int jj = 0; jj < 8; ++jj) {
        int d = dco + jj;
        int byte = d*144 + vr*2;
        byte ^= ((d >> 3) & 7) << 4;
        *(u16*)((char*)Vts + byte) = (u16)vv[jj];
      }
    }
    __syncthreads();

    // bias straight into the accumulator:
    // D(reg jr, lane) = S^T[key = n*16+g*4+jr][query = lr]
    f32x4 Sa[4];
    #pragma unroll
    for (int n = 0; n < 4; ++n) {
      ushort4 bb = *(const ushort4*)&bm[bmrow + c0 + n*16 + g*4];
      Sa[n][0] = bf2f(bb.x); Sa[n][1] = bf2f(bb.y);
      Sa[n][2] = bf2f(bb.z); Sa[n][3] = bf2f(bb.w);
    }
    // S^T = K Q^T + bias
    #pragma unroll
    for (int kc = 0; kc < 2; ++kc)
      #pragma unroll
      for (int n = 0; n < 4; ++n) {
        bf16x8 kb = *(const bf16x8*)&Ks[(n*16 + lr)*72 + kc*32 + g*8];
        Sa[n] = __builtin_amdgcn_mfma_f32_16x16x32_bf16(kb, qf[kc], Sa[n], 0, 0, 0);
      }

    // per-lane online softmax for query lr (16 owned keys), reduce across g
    float tmax = -1e30f;
    #pragma unroll
    for (int n = 0; n < 4; ++n)
      #pragma unroll
      for (int jr = 0; jr < 4; ++jr)
        tmax = fmaxf(tmax, Sa[n][jr]);
    tmax = fmaxf(tmax, __shfl_xor(tmax, 16, 64));
    tmax = fmaxf(tmax, __shfl_xor(tmax, 32, 64));
    float mnew = fmaxf(mr, tmax);
    float alpha_me = __expf(mr - mnew);
    mr = mnew;
    float ps = 0.f;
    #pragma unroll
    for (int n = 0; n < 4; ++n)
      #pragma unroll
      for (int jr = 0; jr < 4; ++jr) {
        float p = __expf(Sa[n][jr] - mnew);
        Sa[n][jr] = p;
        ps += p;
      }
    ps += __shfl_xor(ps, 16, 64);
    ps += __shfl_xor(ps, 32, 64);
    ls = ls * alpha_me + ps;

    // transpose alpha to the PV accumulator layout (query = g*4+jr)
    float av[4];
    #pragma unroll
    for (int jr = 0; jr < 4; ++jr)
      av[jr] = __shfl(alpha_me, g*4 + jr, 16);
    #pragma unroll
    for (int n = 0; n < 4; ++n)
      #pragma unroll
      for (int jr = 0; jr < 4; ++jr)
        Oa[n][jr] *= av[jr];

    // P -> LDS in round-1 layout Ps[w][q][key]: q=lr, keys n*16+g*4+0..3
    #pragma unroll
    for (int n = 0; n < 4; ++n) {
      ushort4 pk;
      pk.x = f2bf(Sa[n][0]); pk.y = f2bf(Sa[n][1]);
      pk.z = f2bf(Sa[n][2]); pk.w = f2bf(Sa[n][3]);
      *(ushort4*)&Ps[w][lr*72 + n*16 + g*4] = pk;
    }
    // rule-18: all P ds_writes retire before any P ds_read
    __asm__ volatile("s_waitcnt lgkmcnt(0)" ::: "memory");
    __builtin_amdgcn_sched_barrier(0);

    // O += P @ V   (round-1 verbatim)
    #pragma unroll
    for (int kc = 0; kc < 2; ++kc) {
      bf16x8 pa = *(const bf16x8*)&Ps[w][lr*72 + kc*32 + g*8];
      #pragma unroll
      for (int n = 0; n < 4; ++n) {
        int d = n*16 + lr;
        int byte = d*144 + (kc*32 + g*8)*2;
        byte ^= ((d >> 3) & 7) << 4;
        bf16x8 vb = *(const bf16x8*)((const char*)Vts + byte);
        Oa[n] = __builtin_amdgcn_mfma_f32_16x16x32_bf16(pa, vb, Oa[n], 0, 0, 0);
      }
    }
  }

  // transpose 1/ls to PV layout, then round-1 verbatim store
  float lv[4];
  #pragma unroll
  for (int jr = 0; jr < 4; ++jr)
    lv[jr] = 1.f / __shfl(ls, g*4 + jr, 16);
  #pragma unroll
  for (int n = 0; n < 4; ++n) {
    #pragma unroll
    for (int jr = 0; jr < 4; ++jr) {
      float o = Oa[n][jr] * lv[jr];
      int row = i0 + w*16 + g*4 + jr;
      vals[(size_t)row*HDIM + hoff + n*16 + lr] = f2bf(o);
    }
  }
}

extern "C" void kernel_launch(void* const* d_in, const int* in_sizes, int n_in,
                              void* d_out, int out_size, void* d_ws, size_t ws_size,
                              hipStream_t stream) {
  const float* q    = (const float*)d_in[0];
  const float* k    = (const float*)d_in[1];
  const float* v    = (const float*)d_in[2];
  const float* bias = (const float*)d_in[3];
  const int*   mask = (const int*)d_in[4];
  const float* Wq   = (const float*)d_in[5];
  const float* bq   = (const float*)d_in[6];
  const float* Wk   = (const float*)d_in[7];
  const float* bk   = (const float*)d_in[8];
  const float* Wv   = (const float*)d_in[9];
  const float* bv   = (const float*)d_in[10];
  const float* Wo1  = (const float*)d_in[11];
  const float* bo1  = (const float*)d_in[12];
  const float* Wo2  = (const float*)d_in[13];
  const float* bo2  = (const float*)d_in[14];

  float* out = (float*)d_out;
  float* bias_out = out + (size_t)NT * DIN_;

  char* ws = (char*)d_ws;
  u16* bm    = (u16*)ws; ws += (size_t)NT*NT*2;
  u16* qh    = (u16*)ws; ws += (size_t)NT*HDIM*2;
  u16* kh    = (u16*)ws; ws += (size_t)NT*HDIM*2;
  u16* vh    = (u16*)ws; ws += (size_t)NT*HDIM*2;
  u16* vals  = (u16*)ws; ws += (size_t)NT*HDIM*2;
  u16* wqb   = (u16*)ws; ws += (size_t)HDIM*DIN_*2;
  u16* wkb   = (u16*)ws; ws += (size_t)HDIM*DIN_*2;
  u16* wvb   = (u16*)ws; ws += (size_t)HDIM*DIN_*2;
  u16* wo1b  = (u16*)ws; ws += (size_t)HDIM*HDIM*2;
  u16* wo2b  = (u16*)ws; ws += (size_t)DIN_*HDIM*2;
  u16* t1    = qh;  // reuse: qh dead after attention

  cvtw_k<<<dim3(1024, 5), 256, 0, stream>>>(Wq, Wk, Wv, Wo1, Wo2,
                                            wqb, wkb, wvb, wo1b, wo2b);
  prep_k<<<dim3(NT*NT/4/256), 256, 0, stream>>>(bias, mask, bm, bias_out);

  // fused projections (q scaled by 1/sqrt(D))
  qkv_k<<<dim3(NT/128, 24), 256, 0, stream>>>(q, k, v, wqb, bq, wkb, bk, wvb, bv,
                                              qh, kh, vh);

  attn_k<<<dim3(NT/64, NH), 256, 0, stream>>>(qh, kh, vh, bm, vals);

  gemm_k<1,1><<<dim3(NT/128, HDIM/128), 256, 0, stream>>>(vals, wo1b, bo1, t1, HDIM, HDIM, 1.0f);
  gemm_k<1,2><<<dim3(NT/128, DIN_/128), 256, 0, stream>>>(t1, wo2b, bo2, out, DIN_, HDIM, 1.0f);
}

// Round 10
// 411.566 us; speedup vs baseline: 1.3071x; 1.0159x over previous
//
#include <hip/hip_runtime.h>
#include <hip/hip_bf16.h>

#define NT 3072
#define DIN_ 512
#define NH 16
#define DH 64
#define HDIM 1024

typedef unsigned short u16;
typedef unsigned int u32;
typedef short short8 __attribute__((ext_vector_type(8)));
typedef float f32x4 __attribute__((ext_vector_type(4)));
typedef __bf16 bf16x8 __attribute__((ext_vector_type(8)));

__device__ __forceinline__ u16 f2bf(float f){
  union { float f; unsigned u; } v; v.f = f;
  unsigned r = v.u + 0x7fffu + ((v.u >> 16) & 1u);
  return (u16)(r >> 16);
}
__device__ __forceinline__ float bf2f(u16 b){
  union { unsigned u; float f; } v; v.u = ((unsigned)b) << 16;
  return v.f;
}

// XOR swizzle for 128-BYTE-stride LDS tiles (64 u16/row, no padding).
// Row r occupies exactly the 128-aligned window [r*128, r*128+127]; the XOR
// permutes bits 4-6 of colbyte only -> provably injective, and spreads the
// "16 lanes read the same 16B column slot of 16 different rows" MFMA pattern
// across 8 slots (2 lanes/bank-group, free per m136).
__device__ __forceinline__ char* swz(void* base, int row, int colbyte){
  return (char*)base + row*128 + (colbyte ^ ((row & 7) << 4));
}
__device__ __forceinline__ const char* swz(const void* base, int row, int colbyte){
  return (const char*)base + row*128 + (colbyte ^ ((row & 7) << 4));
}

// ---------------- prep: bm = mask ? bias : -1e30 (bf16); bias passthrough ----
__global__ __launch_bounds__(256) void prep_k(
    const float* __restrict__ bias, const int* __restrict__ mask,
    u16* __restrict__ bm, float* __restrict__ bias_out)
{
  int i = blockIdx.x * 256 + threadIdx.x;   // groups of 4 elements
  f32x4 b = ((const f32x4*)bias)[i];
  int4 m = ((const int4*)mask)[i];
  ((f32x4*)bias_out)[i] = b;
  const int mm[4] = {m.x, m.y, m.z, m.w};
  union { u16 s[4]; unsigned long long ll; } pk;
  #pragma unroll
  for (int j = 0; j < 4; ++j)
    pk.s[j] = mm[j] ? f2bf(b[j]) : f2bf(-1e30f);
  ((unsigned long long*)bm)[i] = pk.ll;
}

// ---------------- convert the 5 weight matrices to bf16 (once) --------------
__global__ __launch_bounds__(256) void cvtw_k(
    const float* __restrict__ Wq, const float* __restrict__ Wk,
    const float* __restrict__ Wv, const float* __restrict__ Wo1,
    const float* __restrict__ Wo2,
    u16* __restrict__ wqb, u16* __restrict__ wkb, u16* __restrict__ wvb,
    u16* __restrict__ wo1b, u16* __restrict__ wo2b)
{
  const float* src; u16* dst; int n4;
  switch (blockIdx.y) {
    case 0: src = Wq;  dst = wqb;  n4 = HDIM*DIN_/4; break;
    case 1: src = Wk;  dst = wkb;  n4 = HDIM*DIN_/4; break;
    case 2: src = Wv;  dst = wvb;  n4 = HDIM*DIN_/4; break;
    case 3: src = Wo1; dst = wo1b; n4 = HDIM*HDIM/4; break;
    default: src = Wo2; dst = wo2b; n4 = DIN_*HDIM/4; break;
  }
  int i = blockIdx.x * 256 + threadIdx.x;
  if (i >= n4) return;
  f32x4 v = ((const f32x4*)src)[i];
  ushort4 o;
  o.x = f2bf(v[0]); o.y = f2bf(v[1]); o.z = f2bf(v[2]); o.w = f2bf(v[3]);
  ((ushort4*)dst)[i] = o;
}

// ---------------- shared 128x128 bf16-MFMA GEMM body: C = A @ W^T + bvec ----
// W pre-converted bf16. A fp32 (A_BF16=0) or bf16 (A_BF16=1).
// EPI 0: bf16 out, x=(acc+b)*scale ; EPI 1: bf16 out, mish ; EPI 2: f32 out ;
// EPI 3: bf16 out TRANSPOSED store (C^T[col][row], Cptr is [Nc][NT])
template<int A_BF16, int EPI>
__device__ __forceinline__ void gemm_body(
    const void* __restrict__ Aptr, const u16* __restrict__ W,
    const float* __restrict__ bvec, void* __restrict__ Cptr,
    int Nc, int K, float scale, int bm0, int bn0,
    u16* As, u16* Bs)
{
  const int tid = threadIdx.x;
  const int lane = tid & 63;
  const int wid = tid >> 6;
  const int wr = wid >> 1, wc = wid & 1;
  const int g = lane >> 4, lr = lane & 15;

  f32x4 acc[4][4] = {};

  for (int k0 = 0; k0 < K; k0 += 32) {
    __syncthreads();
    if (A_BF16) {
      const u16* A = (const u16*)Aptr;
      #pragma unroll
      for (int it = 0; it < 2; ++it) {
        int e = it*2048 + tid*8;
        int r = e >> 5, kk = e & 31;
        *(short8*)&As[r*40 + kk] = *(const short8*)&A[(size_t)(bm0+r)*K + k0 + kk];
      }
    } else {
      const float* A = (const float*)Aptr;
      #pragma unroll
      for (int it = 0; it < 4; ++it) {
        int e = it*1024 + tid*4;
        int r = e >> 5, kk = e & 31;
        f32x4 v = *(const f32x4*)&A[(size_t)(bm0+r)*K + k0 + kk];
        union { u16 s[4]; unsigned long long ll; } pk;
        #pragma unroll
        for (int jj = 0; jj < 4; ++jj) pk.s[jj] = f2bf(v[jj]);
        *(unsigned long long*)&As[r*40 + kk] = pk.ll;
      }
    }
    {
      #pragma unroll
      for (int it = 0; it < 2; ++it) {
        int e = it*2048 + tid*8;
        int r = e >> 5, kk = e & 31;
        *(short8*)&Bs[r*40 + kk] = *(const short8*)&W[(size_t)(bn0+r)*K + k0 + kk];
      }
    }
    __syncthreads();
    bf16x8 af[4], bfr[4];
    #pragma unroll
    for (int m = 0; m < 4; ++m)
      af[m] = *(const bf16x8*)&As[(wr*64 + m*16 + lr)*40 + g*8];
    #pragma unroll
    for (int n = 0; n < 4; ++n)
      bfr[n] = *(const bf16x8*)&Bs[(wc*64 + n*16 + lr)*40 + g*8];
    #pragma unroll
    for (int m = 0; m < 4; ++m)
      #pragma unroll
      for (int n = 0; n < 4; ++n)
        acc[m][n] = __builtin_amdgcn_mfma_f32_16x16x32_bf16(af[m], bfr[n], acc[m][n], 0, 0, 0);
  }

  #pragma unroll
  for (int m = 0; m < 4; ++m) {
    const int row0 = bm0 + wr*64 + m*16 + g*4;
    #pragma unroll
    for (int n = 0; n < 4; ++n) {
      const int col = bn0 + wc*64 + n*16 + lr;
      const float bb = bvec[col];
      if (EPI == 3) {
        ushort4 pk;
        pk.x = f2bf((acc[m][n][0] + bb) * scale);
        pk.y = f2bf((acc[m][n][1] + bb) * scale);
        pk.z = f2bf((acc[m][n][2] + bb) * scale);
        pk.w = f2bf((acc[m][n][3] + bb) * scale);
        *(ushort4*)&((u16*)Cptr)[(size_t)col*NT + row0] = pk;
      } else {
        #pragma unroll
        for (int j = 0; j < 4; ++j) {
          float x = acc[m][n][j] + bb;
          if (EPI == 0) x *= scale;
          if (EPI == 1) {
            float sp = (x > 15.f) ? x : log1pf(__expf(x));
            x = x * tanhf(sp);
          }
          if (EPI == 2)
            ((float*)Cptr)[(size_t)(row0+j)*Nc + col] = x;
          else
            ((u16*)Cptr)[(size_t)(row0+j)*Nc + col] = f2bf(x);
        }
      }
    }
  }
}

template<int A_BF16, int EPI>
__global__ __launch_bounds__(256) void gemm_k(
    const void* __restrict__ Aptr, const u16* __restrict__ W,
    const float* __restrict__ bvec, void* __restrict__ Cptr,
    int Nc, int K, float scale)
{
  __shared__ __align__(16) u16 As[128*40];
  __shared__ __align__(16) u16 Bs[128*40];
  gemm_body<A_BF16, EPI>(Aptr, W, bvec, Cptr, Nc, K, scale,
                         blockIdx.x*128, blockIdx.y*128, As, Bs);
}

// fused q/k/v projections: blockIdx.y selects source (grid 24 x 24)
// V is stored TRANSPOSED (vt[HDIM][NT]) for the attention PV step.
__global__ __launch_bounds__(256) void qkv_k(
    const float* __restrict__ q, const float* __restrict__ k,
    const float* __restrict__ v,
    const u16* __restrict__ wqb, const float* __restrict__ bq,
    const u16* __restrict__ wkb, const float* __restrict__ bk,
    const u16* __restrict__ wvb, const float* __restrict__ bv,
    u16* __restrict__ qh, u16* __restrict__ kh, u16* __restrict__ vt)
{
  __shared__ __align__(16) u16 As[128*40];
  __shared__ __align__(16) u16 Bs[128*40];
  const int sel = blockIdx.y >> 3;
  if (sel == 2) {
    gemm_body<0, 3>(v, wvb, bv, vt, HDIM, DIN_, 1.0f,
                    blockIdx.x*128, (blockIdx.y & 7)*128, As, Bs);
  } else {
    const float* A    = sel == 0 ? q   : k;
    const u16* W      = sel == 0 ? wqb : wkb;
    const float* bvec = sel == 0 ? bq  : bk;
    u16* C            = sel == 0 ? qh  : kh;
    const float scale = sel == 0 ? 0.125f : 1.0f;
    gemm_body<0, 0>(A, W, bvec, C, HDIM, DIN_, scale,
                    blockIdx.x*128, (blockIdx.y & 7)*128, As, Bs);
  }
}

// ---------------- flash attention: 64 q-rows x 1 head per block -------------
// R7-validated swapped-QK softmax + round-1 PV. V pre-transposed in global
// (vt) so staging is pure vector copies. Ks/Vts/Ps use 128-byte-stride LDS
// tiles with the injective (row&7)<<4 colbyte XOR swizzle on BOTH sides.
__global__ __launch_bounds__(256) void attn_k(
    const u16* __restrict__ qh, const u16* __restrict__ kh,
    const u16* __restrict__ vt, const u16* __restrict__ bm,
    u16* __restrict__ vals)
{
  __shared__ __align__(16) u16 Qs[64*72];     // unswizzled, read once
  __shared__ __align__(16) u16 Ks[64*64];     // [token][d], swizzled
  __shared__ __align__(16) u16 Vts[64*64];    // V^T [d][token], swizzled
  __shared__ __align__(16) u16 PsB[4][16*64]; // per-wave P [q][key], swizzled

  const int tid = threadIdx.x;
  const int lane = tid & 63;
  const int w = tid >> 6;
  const int g = lane >> 4, lr = lane & 15;
  const int i0 = blockIdx.x * 64;
  const int hoff = blockIdx.y * DH;

  // stage Q tile [64][64] (unswizzled; read once)
  #pragma unroll
  for (int it = 0; it < 2; ++it) {
    int c = it*256 + tid;
    int r = c >> 3, co = (c & 7) * 8;
    *(short8*)&Qs[r*72 + co] = *(const short8*)&qh[(size_t)(i0 + r)*HDIM + hoff + co];
  }
  __syncthreads();
  bf16x8 qf[2];
  #pragma unroll
  for (int kc = 0; kc < 2; ++kc)
    qf[kc] = *(const bf16x8*)&Qs[(w*16 + lr)*72 + kc*32 + g*8];

  u16* Psw = &PsB[w][0];

  f32x4 Oa[4] = {};
  float mr = -1e30f, ls = 0.f;                 // state for query row lr
  const size_t bmrow = (size_t)(i0 + w*16 + lr) * NT;

  for (int j = 0; j < NT/64; ++j) {
    const int c0 = j * 64;
    __syncthreads();
    // stage K [64][64], swizzled write
    #pragma unroll
    for (int it = 0; it < 2; ++it) {
      int c = it*256 + tid;
      int r = c >> 3, co = (c & 7) * 8;
      *(short8*)swz(Ks, r, co*2) = *(const short8*)&kh[(size_t)(c0 + r)*HDIM + hoff + co];
    }
    // stage V^T [d][token] from vt (pure vector copy), swizzled write
    #pragma unroll
    for (int it = 0; it < 2; ++it) {
      int c = it*256 + tid;
      int r = c >> 3, co = (c & 7) * 8;
      *(short8*)swz(Vts, r, co*2) = *(const short8*)&vt[(size_t)(hoff + r)*NT + c0 + co];
    }
    __syncthreads();

    // bias straight into the accumulator:
    // D(reg jr, lane) = S^T[key = n*16+g*4+jr][query = lr]
    f32x4 Sa[4];
    #pragma unroll
    for (int n = 0; n < 4; ++n) {
      ushort4 bb = *(const ushort4*)&bm[bmrow + c0 + n*16 + g*4];
      Sa[n][0] = bf2f(bb.x); Sa[n][1] = bf2f(bb.y);
      Sa[n][2] = bf2f(bb.z); Sa[n][3] = bf2f(bb.w);
    }
    // S^T = K Q^T + bias
    #pragma unroll
    for (int kc = 0; kc < 2; ++kc)
      #pragma unroll
      for (int n = 0; n < 4; ++n) {
        bf16x8 kb = *(const bf16x8*)swz(Ks, n*16 + lr, (kc*32 + g*8)*2);
        Sa[n] = __builtin_amdgcn_mfma_f32_16x16x32_bf16(kb, qf[kc], Sa[n], 0, 0, 0);
      }

    // per-lane online softmax for query lr (16 owned keys), reduce across g
    float tmax = -1e30f;
    #pragma unroll
    for (int n = 0; n < 4; ++n)
      #pragma unroll
      for (int jr = 0; jr < 4; ++jr)
        tmax = fmaxf(tmax, Sa[n][jr]);
    tmax = fmaxf(tmax, __shfl_xor(tmax, 16, 64));
    tmax = fmaxf(tmax, __shfl_xor(tmax, 32, 64));
    float mnew = fmaxf(mr, tmax);
    float alpha_me = __expf(mr - mnew);
    mr = mnew;
    float ps = 0.f;
    #pragma unroll
    for (int n = 0; n < 4; ++n)
      #pragma unroll
      for (int jr = 0; jr < 4; ++jr) {
        float p = __expf(Sa[n][jr] - mnew);
        Sa[n][jr] = p;
        ps += p;
      }
    ps += __shfl_xor(ps, 16, 64);
    ps += __shfl_xor(ps, 32, 64);
    ls = ls * alpha_me + ps;

    // transpose alpha to the PV accumulator layout (query = g*4+jr)
    float av[4];
    #pragma unroll
    for (int jr = 0; jr < 4; ++jr)
      av[jr] = __shfl(alpha_me, g*4 + jr, 16);
    #pragma unroll
    for (int n = 0; n < 4; ++n)
      #pragma unroll
      for (int jr = 0; jr < 4; ++jr)
        Oa[n][jr] *= av[jr];

    // P -> LDS Psw[q=lr][key], swizzled ushort4 stores
    #pragma unroll
    for (int n = 0; n < 4; ++n) {
      ushort4 pk;
      pk.x = f2bf(Sa[n][0]); pk.y = f2bf(Sa[n][1]);
      pk.z = f2bf(Sa[n][2]); pk.w = f2bf(Sa[n][3]);
      *(ushort4*)swz(Psw, lr, (n*16 + g*4)*2) = pk;
    }
    // rule-18: all P ds_writes retire before any P ds_read
    __asm__ volatile("s_waitcnt lgkmcnt(0)" ::: "memory");
    __builtin_amdgcn_sched_barrier(0);

    // O += P @ V   (round-1 PV, swizzled reads)
    #pragma unroll
    for (int kc = 0; kc < 2; ++kc) {
      bf16x8 pa = *(const bf16x8*)swz(Psw, lr, (kc*32 + g*8)*2);
      #pragma unroll
      for (int n = 0; n < 4; ++n) {
        bf16x8 vb = *(const bf16x8*)swz(Vts, n*16 + lr, (kc*32 + g*8)*2);
        Oa[n] = __builtin_amdgcn_mfma_f32_16x16x32_bf16(pa, vb, Oa[n], 0, 0, 0);
      }
    }
  }

  // transpose 1/ls to PV layout, then round-1 verbatim store
  float lv[4];
  #pragma unroll
  for (int jr = 0; jr < 4; ++jr)
    lv[jr] = 1.f / __shfl(ls, g*4 + jr, 16);
  #pragma unroll
  for (int n = 0; n < 4; ++n) {
    #pragma unroll
    for (int jr = 0; jr < 4; ++jr) {
      float o = Oa[n][jr] * lv[jr];
      int row = i0 + w*16 + g*4 + jr;
      vals[(size_t)row*HDIM + hoff + n*16 + lr] = f2bf(o);
    }
  }
}

extern "C" void kernel_launch(void* const* d_in, const int* in_sizes, int n_in,
                              void* d_out, int out_size, void* d_ws, size_t ws_size,
                              hipStream_t stream) {
  const float* q    = (const float*)d_in[0];
  const float* k    = (const float*)d_in[1];
  const float* v    = (const float*)d_in[2];
  const float* bias = (const float*)d_in[3];
  const int*   mask = (const int*)d_in[4];
  const float* Wq   = (const float*)d_in[5];
  const float* bq   = (const float*)d_in[6];
  const float* Wk   = (const float*)d_in[7];
  const float* bk   = (const float*)d_in[8];
  const float* Wv   = (const float*)d_in[9];
  const float* bv   = (const float*)d_in[10];
  const float* Wo1  = (const float*)d_in[11];
  const float* bo1  = (const float*)d_in[12];
  const float* Wo2  = (const float*)d_in[13];
  const float* bo2  = (const float*)d_in[14];

  float* out = (float*)d_out;
  float* bias_out = out + (size_t)NT * DIN_;

  char* ws = (char*)d_ws;
  u16* bm    = (u16*)ws; ws += (size_t)NT*NT*2;
  u16* qh    = (u16*)ws; ws += (size_t)NT*HDIM*2;
  u16* kh    = (u16*)ws; ws += (size_t)NT*HDIM*2;
  u16* vt    = (u16*)ws; ws += (size_t)HDIM*NT*2;   // V^T [HDIM][NT]
  u16* vals  = (u16*)ws; ws += (size_t)NT*HDIM*2;
  u16* wqb   = (u16*)ws; ws += (size_t)HDIM*DIN_*2;
  u16* wkb   = (u16*)ws; ws += (size_t)HDIM*DIN_*2;
  u16* wvb   = (u16*)ws; ws += (size_t)HDIM*DIN_*2;
  u16* wo1b  = (u16*)ws; ws += (size_t)HDIM*HDIM*2;
  u16* wo2b  = (u16*)ws; ws += (size_t)DIN_*HDIM*2;
  u16* t1    = qh;  // reuse: qh dead after attention

  cvtw_k<<<dim3(1024, 5), 256, 0, stream>>>(Wq, Wk, Wv, Wo1, Wo2,
                                            wqb, wkb, wvb, wo1b, wo2b);
  prep_k<<<dim3(NT*NT/4/256), 256, 0, stream>>>(bias, mask, bm, bias_out);

  // fused projections (q scaled by 1/sqrt(D); V emitted transposed)
  qkv_k<<<dim3(NT/128, 24), 256, 0, stream>>>(q, k, v, wqb, bq, wkb, bk, wvb, bv,
                                              qh, kh, vt);

  attn_k<<<dim3(NT/64, NH), 256, 0, stream>>>(qh, kh, vt, bm, vals);

  gemm_k<1,1><<<dim3(NT/128, HDIM/128), 256, 0, stream>>>(vals, wo1b, bo1, t1, HDIM, HDIM, 1.0f);
  gemm_k<1,2><<<dim3(NT/128, DIN_/128), 256, 0, stream>>>(t1, wo2b, bo2, out, DIN_, HDIM, 1.0f);
}